// Round 20
// baseline (263.086 us; speedup 1.0000x reference)
//
#include <hip/hip_runtime.h>
#include <hip/hip_bf16.h>

// Problem constants
#define CIN_   26
#define HIN_   721
#define WIN_   1440
#define K_     9
#define HOUT_  360
#define KH_    9
#define KW_    9
#define COUT_  256
#define WOUT_  720

#define WT     16                 // w-tile width
#define TILES  3                  // w-tiles per block (48 output cols)
#define XCOLS3 104                // staged cols: 2*48 + 8
#define XSP3   104                // xs row pitch in u16 (208 B, 16B-divisible)
#define CCH    7                  // c-chunk (4 rounds: 7,7,7,5)
#define CK     (CIN_ * K_)        // 234
#define NKS2   9                  // phase-2 k-steps (k' = c*10+m, padded 288)
#define ACCP2  296                // u16 pitch: 592 B rows (16B aligned)
#define NMT    (COUT_ / 16)       // 16 m-tiles
#define NXCD   8

typedef short bf16x8 __attribute__((ext_vector_type(8)));
typedef float f32x4  __attribute__((ext_vector_type(4)));

// Fragment-ordered bf16 weight in k'-layout: [(mt*NKS2+ks)*64 + lane]*8 + j  (144 KB)
__device__ unsigned short g_whi[NMT * NKS2 * 64 * 8];
// Per-h psi A-fragments for phase 1: [(h*3 + ks)*64 + lane]*8 + e  (1.1 MB)
__device__ unsigned short g_pfrag[HOUT_ * 3 * 64 * 8];

__device__ __forceinline__ unsigned short f2bf_rne(float f) {
    union { float f; unsigned u; } v; v.f = f;
    unsigned u = v.u;
    unsigned r = (u + 0x7FFFu + ((u >> 16) & 1u)) >> 16;
    return (unsigned short)r;
}
__device__ __forceinline__ unsigned pack_bf2(float a, float b) {
    const __hip_bfloat162 bv = __float22bfloat162_rn(make_float2(a, b));
    return *reinterpret_cast<const unsigned*>(&bv);
}

// A-operand layout for mfma_f32_16x16x32_bf16: row m = lane&15, k = ks*32 + (lane>>4)*8 + j
// k' decoding: c = k'/10, m = k'%10; m==9 or k'>=260 -> zero
__global__ void prep_weight_kernel(const float* __restrict__ weight) {
    const int bid  = blockIdx.x;        // 0..143  (mt*NKS2 + ks)
    const int mt   = bid / NKS2;
    const int ks   = bid % NKS2;
    const int lane = threadIdx.x;       // 0..63
    const int row  = mt * 16 + (lane & 15);
    const int k0   = ks * 32 + (lane >> 4) * 8;
    const int base = ((mt * NKS2 + ks) * 64 + lane) * 8;
    #pragma unroll
    for (int j = 0; j < 8; ++j) {
        const int kp = k0 + j;
        float w = 0.f;
        if (kp < 260) {
            const int c = kp / 10, m = kp % 10;
            if (m < 9) w = weight[row * CK + c * 9 + m];
        }
        g_whi[base + j] = f2bf_rne(w);
    }
}

// Phase-1 contraction ordering over the 81 (dh,dw) taps, padded to 96:
//   slot s in [0,72):  dh = s>>3, dw = s&7    (adjacent-dw pairs)
//   slot s in [72,81): dh = s-72, dw = 8      (the dw=8 singles)
//   slot s in [81,96): zero padding
__global__ void prep_psi_kernel(const float* __restrict__ psi) {
    const int h    = blockIdx.x;        // 0..359
    const int lane = threadIdx.x;       // 0..63
    const int m    = lane & 15;
    const int kg   = lane >> 4;
    #pragma unroll
    for (int ks = 0; ks < 3; ++ks) {
        const int base = ((h * 3 + ks) * 64 + lane) * 8;
        #pragma unroll
        for (int e = 0; e < 8; ++e) {
            const int s = ks * 32 + kg * 8 + e;
            float v = 0.f;
            if (m < 9) {
                if (s < 72)      v = psi[(m * HOUT_ + h) * 81 + (s >> 3) * 9 + (s & 7)];
                else if (s < 81) v = psi[(m * HOUT_ + h) * 81 + (s - 72) * 9 + 8];
            }
            g_pfrag[base + e] = f2bf_rne(v);
        }
    }
}

__global__ __launch_bounds__(256, 3)
void disco_fused_kernel(const float* __restrict__ x,
                        const int*   __restrict__ hi_base,
                        float* __restrict__ out)
{
    __shared__ unsigned short xs_bf[CCH * KH_][XSP3];                 // 63*104*2 = 13104 B
    __shared__ __align__(16) unsigned short acc_s[TILES][WT][ACCP2];  // 3*16*296*2 = 28416 B
                                                                      // total 41520 B -> 3 blocks/CU

    // grid 5400 = 8 XCDs * 675; per XCD 675 groups cover 45 h * 15 groups
    const int b   = blockIdx.x;
    const int xcd = b & (NXCD - 1);
    const int j   = b >> 3;             // 0..674
    const int h   = xcd * 45 + j / 15;
    const int w0  = ((j % 15) * 3) * WT;   // base of 48-wide group
    const int tid = threadIdx.x;

    const int hib = hi_base[h];         // in [0, 716]

    // ---- zero acc_s k'-padding cols [260,288) for all 3 tiles ----
    for (int e = tid; e < TILES * 16 * 14; e += 256) {
        const int q  = e / 224;
        const int r2 = e % 224;
        *reinterpret_cast<unsigned*>(&acc_s[q][r2 / 14][260 + 2 * (r2 % 14)]) = 0u;
    }

    const int lane = tid & 63;
    const int wid  = tid >> 6;          // 4 waves
    const int n    = lane & 15;
    const int kg   = lane >> 4;

    // ---- load psi A-fragments (precomputed, coalesced 16B/lane) ----
    bf16x8 afrag[3];
    #pragma unroll
    for (int ks = 0; ks < 3; ++ks)
        afrag[ks] = *(const bf16x8*)&g_pfrag[((h * 3 + ks) * 64 + lane) * 8];

    const int c0 = 2 * w0 - 4;          // in [-4, 1340], divisible by 4
    const char* xsb = (const char*)&xs_bf[0][0];

    // ---- 4 rounds: stage c-chunk -> barrier -> phase-1 chunk -> barrier ----
    for (int rd = 0; rd < 4; ++rd) {
        const int cbase = rd * CCH;
        const int nc    = (rd == 3) ? (CIN_ - 3 * CCH) : CCH;   // 7,7,7,5

        // stage chunk as bf16 float4-chunks (16B-aligned, never wrap-straddling)
        for (int i = tid; i < nc * KH_ * (XCOLS3 / 4); i += 256) {
            const int q  = i % (XCOLS3 / 4);   // chunk cols 4q..4q+3
            const int lr = i / (XCOLS3 / 4);   // local row = cc*9 + dh
            const int dh = lr % KH_;
            const int c  = cbase + lr / KH_;
            int r = hib + dh;
            if (r > HIN_ - 1) r = HIN_ - 1;
            int g = c0 + 4 * q;
            if (g < 0)          g += WIN_;
            else if (g >= WIN_) g -= WIN_;
            const float4 v = *reinterpret_cast<const float4*>(x + ((size_t)c * HIN_ + r) * WIN_ + g);
            uint2 dv;
            dv.x = pack_bf2(v.x, v.y);
            dv.y = pack_bf2(v.z, v.w);
            *reinterpret_cast<uint2*>(&xs_bf[lr][4 * q]) = dv;
        }
        __syncthreads();

        // phase 1 on this chunk: 3 tiles share afrag; B-frag differs by +64B per tile
        for (int cc = wid; cc < nc; cc += 4) {
            const int c    = cbase + cc;
            const int rowb = cc * (KH_ * XSP3 * 2);   // cc*1872
            f32x4 ct0 = {0.f, 0.f, 0.f, 0.f}, ct1 = ct0, ct2 = ct0;

            #pragma unroll
            for (int ks = 0; ks < 3; ++ks) {
                #define P1_TILE(CQ, QQ)                                                          \
                do {                                                                             \
                    union { bf16x8 v; unsigned d[4]; unsigned short u[8]; } bf;                  \
                    const int tb = rowb + 64 * (QQ) + 4 * n;                                     \
                    if (ks < 2 || kg == 0) {                                                     \
                        const char* p = xsb + tb + (ks * 4 + kg) * (XSP3 * 2);                   \
                        bf.d[0] = *(const unsigned*)(p);                                         \
                        bf.d[1] = *(const unsigned*)(p + 4);                                     \
                        bf.d[2] = *(const unsigned*)(p + 8);                                     \
                        bf.d[3] = *(const unsigned*)(p + 12);                                    \
                    } else if (kg == 1) {                                                        \
                        _Pragma("unroll")                                                        \
                        for (int e = 0; e < 8; ++e)                                              \
                            bf.u[e] = *(const unsigned short*)(xsb + tb + e * (XSP3 * 2) + 16);  \
                    } else if (kg == 2) {                                                        \
                        bf.d[0] = bf.d[1] = bf.d[2] = bf.d[3] = 0;                               \
                        bf.u[0] = *(const unsigned short*)(xsb + tb + 8 * (XSP3 * 2) + 16);      \
                    } else {                                                                     \
                        bf.d[0] = bf.d[1] = bf.d[2] = bf.d[3] = 0;                               \
                    }                                                                            \
                    CQ = __builtin_amdgcn_mfma_f32_16x16x32_bf16(afrag[ks], bf.v, CQ, 0, 0, 0);  \
                } while (0)

                P1_TILE(ct0, 0);
                P1_TILE(ct1, 1);
                P1_TILE(ct2, 2);
                #undef P1_TILE
            }

            // writeback: k' = c*10 + kg*4 + r, packed dword pairs
            #define P1_WB(CQ, QQ)                                                                \
            do {                                                                                 \
                if (kg < 2) {                                                                    \
                    unsigned* ap = reinterpret_cast<unsigned*>(&acc_s[QQ][n][c * 10 + kg * 4]);  \
                    ap[0] = pack_bf2(CQ[0], CQ[1]);                                              \
                    ap[1] = pack_bf2(CQ[2], CQ[3]);                                              \
                } else if (kg == 2) {                                                            \
                    *reinterpret_cast<unsigned*>(&acc_s[QQ][n][c * 10 + 8]) =                    \
                        pack_bf2(CQ[0], 0.f);                                                    \
                }                                                                                \
            } while (0)

            P1_WB(ct0, 0);
            P1_WB(ct1, 1);
            P1_WB(ct2, 2);
            #undef P1_WB
        }
        __syncthreads();
    }

    // ---- phase 2: 3 tiles, weight loaded once per ks and reused 3x ----
    f32x4 C[TILES][4];
    #pragma unroll
    for (int q = 0; q < TILES; ++q)
        #pragma unroll
        for (int i = 0; i < 4; ++i)
            C[q][i] = (f32x4){0.f, 0.f, 0.f, 0.f};

    // frag(i, ks) at wp + (i*NKS2 + ks)*512   (u16 units; 512 = 64 lanes * 8)
    const unsigned short* wp = g_whi + ((size_t)(wid * 4) * NKS2 * 64 + lane) * 8;

    bf16x8 wc[4];
    #pragma unroll
    for (int i = 0; i < 4; ++i)
        wc[i] = *(const bf16x8*)(wp + (size_t)i * NKS2 * 512);

    #pragma unroll
    for (int ks = 0; ks < NKS2; ++ks) {
        bf16x8 wn[4];
        if (ks + 1 < NKS2) {
            #pragma unroll
            for (int i = 0; i < 4; ++i)
                wn[i] = *(const bf16x8*)(wp + ((size_t)i * NKS2 + (ks + 1)) * 512);
        }
        #pragma unroll
        for (int q = 0; q < TILES; ++q) {
            const bf16x8 bq = *(const bf16x8*)&acc_s[q][n][ks * 32 + kg * 8];
            C[q][0] = __builtin_amdgcn_mfma_f32_16x16x32_bf16(wc[0], bq, C[q][0], 0, 0, 0);
            C[q][1] = __builtin_amdgcn_mfma_f32_16x16x32_bf16(wc[1], bq, C[q][1], 0, 0, 0);
            C[q][2] = __builtin_amdgcn_mfma_f32_16x16x32_bf16(wc[2], bq, C[q][2], 0, 0, 0);
            C[q][3] = __builtin_amdgcn_mfma_f32_16x16x32_bf16(wc[3], bq, C[q][3], 0, 0, 0);
        }
        if (ks + 1 < NKS2) {
            #pragma unroll
            for (int i = 0; i < 4; ++i) wc[i] = wn[i];
        }
    }

    // ---- epilogue: D layout col = lane&15 (w), row = kg*4 + r ----
    #pragma unroll
    for (int q = 0; q < TILES; ++q) {
        #pragma unroll
        for (int i = 0; i < 4; ++i) {
            const int m0 = (wid * 4 + i) * 16 + kg * 4;
            #pragma unroll
            for (int r = 0; r < 4; ++r) {
                out[(size_t)(m0 + r) * (HOUT_ * WOUT_) + h * WOUT_ + w0 + q * WT + n] = C[q][i][r];
            }
        }
    }
}

extern "C" void kernel_launch(void* const* d_in, const int* in_sizes, int n_in,
                              void* d_out, int out_size, void* d_ws, size_t ws_size,
                              hipStream_t stream)
{
    const float* x       = (const float*)d_in[0];
    const float* psi     = (const float*)d_in[1];
    const float* weight  = (const float*)d_in[2];
    const int*   hi_base = (const int*)d_in[3];
    float* out = (float*)d_out;

    hipLaunchKernelGGL(prep_weight_kernel, dim3(NMT * NKS2), dim3(64), 0, stream, weight);
    hipLaunchKernelGGL(prep_psi_kernel,    dim3(HOUT_),      dim3(64), 0, stream, psi);

    dim3 grid(5400, 1, 1);   // 8 XCDs * 675 groups (3 tiles each)
    dim3 block(256, 1, 1);
    hipLaunchKernelGGL(disco_fused_kernel, grid, block, 0, stream,
                       x, hi_base, out);
}

// Round 21
// 256.883 us; speedup vs baseline: 1.0241x; 1.0241x over previous
//
#include <hip/hip_runtime.h>
#include <hip/hip_bf16.h>

// Problem constants
#define CIN_   26
#define HIN_   721
#define WIN_   1440
#define K_     9
#define HOUT_  360
#define KH_    9
#define KW_    9
#define COUT_  256
#define WOUT_  720

#define WT     16                 // w-tile per block (720/16 = 45 tiles)
#define XSP    48                 // xs row pitch in u16 (96 B)
#define CCH    7                  // c-chunk (4 rounds: 7,7,7,5); chunk rows = 63
#define CK     (CIN_ * K_)        // 234
#define NKS2   9                  // phase-2 k-steps (k' = c*10+m, padded 288)
#define ACCP2  296                // u16 pitch: 592 B rows (16B aligned)
#define NMT    (COUT_ / 16)       // 16 m-tiles
#define NXCD   8
#define HBAND  (HOUT_ / NXCD)     // 45 h-rows per XCD band

typedef short bf16x8 __attribute__((ext_vector_type(8)));
typedef float f32x4  __attribute__((ext_vector_type(4)));

// Fragment-ordered bf16 weight in k'-layout: [(mt*NKS2+ks)*64 + lane]*8 + j  (144 KB)
__device__ unsigned short g_whi[NMT * NKS2 * 64 * 8];
// Per-h psi A-fragments for phase 1: [(h*3 + ks)*64 + lane]*8 + e  (1.1 MB)
__device__ unsigned short g_pfrag[HOUT_ * 3 * 64 * 8];

__device__ __forceinline__ unsigned short f2bf_rne(float f) {
    union { float f; unsigned u; } v; v.f = f;
    unsigned u = v.u;
    unsigned r = (u + 0x7FFFu + ((u >> 16) & 1u)) >> 16;
    return (unsigned short)r;
}
__device__ __forceinline__ unsigned pack_bf2(float a, float b) {
    const __hip_bfloat162 bv = __float22bfloat162_rn(make_float2(a, b));
    return *reinterpret_cast<const unsigned*>(&bv);
}

// A-operand layout for mfma_f32_16x16x32_bf16: row m = lane&15, k = ks*32 + (lane>>4)*8 + j
// k' decoding: c = k'/10, m = k'%10; m==9 or k'>=260 -> zero
__global__ void prep_weight_kernel(const float* __restrict__ weight) {
    const int bid  = blockIdx.x;        // 0..143  (mt*NKS2 + ks)
    const int mt   = bid / NKS2;
    const int ks   = bid % NKS2;
    const int lane = threadIdx.x;       // 0..63
    const int row  = mt * 16 + (lane & 15);
    const int k0   = ks * 32 + (lane >> 4) * 8;
    const int base = ((mt * NKS2 + ks) * 64 + lane) * 8;
    #pragma unroll
    for (int j = 0; j < 8; ++j) {
        const int kp = k0 + j;
        float w = 0.f;
        if (kp < 260) {
            const int c = kp / 10, m = kp % 10;
            if (m < 9) w = weight[row * CK + c * 9 + m];
        }
        g_whi[base + j] = f2bf_rne(w);
    }
}

// Phase-1 contraction ordering over the 81 (dh,dw) taps, padded to 96:
//   slot s in [0,72):  dh = s>>3, dw = s&7    (adjacent-dw pairs)
//   slot s in [72,81): dh = s-72, dw = 8      (the dw=8 singles)
//   slot s in [81,96): zero padding
__global__ void prep_psi_kernel(const float* __restrict__ psi) {
    const int h    = blockIdx.x;        // 0..359
    const int lane = threadIdx.x;       // 0..63
    const int m    = lane & 15;
    const int kg   = lane >> 4;
    #pragma unroll
    for (int ks = 0; ks < 3; ++ks) {
        const int base = ((h * 3 + ks) * 64 + lane) * 8;
        #pragma unroll
        for (int e = 0; e < 8; ++e) {
            const int s = ks * 32 + kg * 8 + e;
            float v = 0.f;
            if (m < 9) {
                if (s < 72)      v = psi[(m * HOUT_ + h) * 81 + (s >> 3) * 9 + (s & 7)];
                else if (s < 81) v = psi[(m * HOUT_ + h) * 81 + (s - 72) * 9 + 8];
            }
            g_pfrag[base + e] = f2bf_rne(v);
        }
    }
}

// barrier that does NOT drain vmcnt: flush own LDS writes, then raw s_barrier
#define LDS_BARRIER()                                      \
    do {                                                   \
        asm volatile("s_waitcnt lgkmcnt(0)" ::: "memory"); \
        __builtin_amdgcn_s_barrier();                      \
    } while (0)

__global__ __launch_bounds__(256, 6)
void disco_fused_kernel(const float* __restrict__ x,
                        const int*   __restrict__ hi_base,
                        float* __restrict__ out)
{
    __shared__ unsigned short xs_bf[2][CCH * KH_][XSP];        // 2*63*48*2 = 12096 B
    __shared__ __align__(16) unsigned short acc_s[WT][ACCP2];  // 9472 B  (21568 -> 7 blocks/CU)

    const int b    = blockIdx.x;        // 0..16199
    const int xcd  = b & (NXCD - 1);
    const int jb   = b >> 3;            // 0..2024
    const int h    = xcd * HBAND + jb / 45;
    const int tile = jb % 45;
    const int w0   = tile * WT;
    const int tid  = threadIdx.x;

    const int hib = hi_base[h];         // in [0, 716]

    // ---- zero acc_s k'-padding cols [260,288) ----
    #pragma unroll
    for (int t = 0; t < 2; ++t) {
        const int e = tid + t * 256;    // 0..511
        if (e < 16 * 28) acc_s[e / 28][260 + e % 28] = 0;
    }

    const int lane = tid & 63;
    const int wid  = tid >> 6;          // 4 waves
    const int n    = lane & 15;
    const int kg   = lane >> 4;

    // ---- load psi A-fragments (precomputed, coalesced 16B/lane) ----
    bf16x8 afrag[3];
    #pragma unroll
    for (int ks = 0; ks < 3; ++ks)
        afrag[ks] = *(const bf16x8*)&g_pfrag[((h * 3 + ks) * 64 + lane) * 8];

    const int c0 = 2 * w0 - 4;          // in [-4, 1404], divisible by 4

    // ---- staging pipeline: ISSUE loads early, WRITE (wait+convert+ds_write) late ----
    // round rd: items = nc*90 float4-chunks (nc = 7,7,7,5)
    #define ISSUE(RD, V, S)                                                          \
    do {                                                                             \
        const int items = ((RD) == 3) ? 450 : 630;                                   \
        _Pragma("unroll")                                                            \
        for (int t = 0; t < 3; ++t) {                                                \
            const int i  = tid + t * 256;                                            \
            const int ii = (i < items) ? i : (items - 1);                            \
            const int q  = ii % 10;                                                  \
            const int lr = ii / 10;                                                  \
            const int dh = lr % 9;                                                   \
            const int c  = (RD) * CCH + lr / 9;                                      \
            int r = hib + dh;                                                        \
            if (r > HIN_ - 1) r = HIN_ - 1;                                          \
            int g = c0 + 4 * q;                                                      \
            if (g < 0)          g += WIN_;                                           \
            else if (g >= WIN_) g -= WIN_;                                           \
            V[t] = *reinterpret_cast<const float4*>(                                 \
                x + ((size_t)c * HIN_ + r) * WIN_ + g);                              \
            S[t] = (i < items) ? (lr * XSP + 4 * q) : -1;                            \
        }                                                                            \
    } while (0)

    #define WRITE(RD, V, S)                                                          \
    do {                                                                             \
        unsigned short* dst = &xs_bf[(RD) & 1][0][0];                                \
        _Pragma("unroll")                                                            \
        for (int t = 0; t < 3; ++t) {                                                \
            if (S[t] >= 0) {                                                         \
                uint2 dv;                                                            \
                dv.x = pack_bf2(V[t].x, V[t].y);                                     \
                dv.y = pack_bf2(V[t].z, V[t].w);                                     \
                *reinterpret_cast<uint2*>(dst + S[t]) = dv;                          \
            }                                                                        \
        }                                                                            \
    } while (0)

    float4 va[3], vb[3];
    int    sa[3], sb[3];

    // prologue: fill buf0; issue chunk-1 loads (stay in flight across raw barrier)
    ISSUE(0, va, sa);
    WRITE(0, va, sa);
    ISSUE(1, vb, sb);
    LDS_BARRIER();

    // ---- 4 rounds: phase-1 on buf[rd&1] while next chunk's loads fly ----
    #pragma unroll
    for (int rd = 0; rd < 4; ++rd) {
        const int nc = (rd == 3) ? (CIN_ - 3 * CCH) : CCH;   // 7,7,7,5
        const char* xsb = (const char*)&xs_bf[rd & 1][0][0];

        for (int cc = wid; cc < nc; cc += 4) {
            const int c    = rd * CCH + cc;
            const int base = cc * (KH_ * XSP * 2) + 4 * n;
            f32x4 C = {0.f, 0.f, 0.f, 0.f};
            #pragma unroll
            for (int ks = 0; ks < 3; ++ks) {
                union { bf16x8 v; unsigned d[4]; unsigned short u[8]; } bf;
                if (ks < 2 || kg == 0) {
                    // pairs: dh = ks*4 + kg (uniform per 16-lane group)
                    const char* p = xsb + base + (ks * 4 + kg) * (XSP * 2);
                    #pragma unroll
                    for (int t = 0; t < 4; ++t)
                        bf.d[t] = *(const unsigned*)(p + 4 * t);
                } else if (kg == 1) {
                    // singles s=72..79: dh = e, dw = 8 -> byte = e*96 + 4n + 16
                    #pragma unroll
                    for (int e = 0; e < 8; ++e)
                        bf.u[e] = *(const unsigned short*)(xsb + base + e * (XSP * 2) + 16);
                } else if (kg == 2) {
                    bf.d[0] = bf.d[1] = bf.d[2] = bf.d[3] = 0;
                    bf.u[0] = *(const unsigned short*)(xsb + base + 8 * (XSP * 2) + 16);  // s=80
                } else {
                    bf.d[0] = bf.d[1] = bf.d[2] = bf.d[3] = 0;
                }
                C = __builtin_amdgcn_mfma_f32_16x16x32_bf16(afrag[ks], bf.v, C, 0, 0, 0);
            }
            // C row m = kg*4 + r -> acc_s[n][c*10 + m], packed pair stores (4B aligned)
            if (kg < 2) {
                unsigned* ap = reinterpret_cast<unsigned*>(&acc_s[n][c * 10 + kg * 4]);
                ap[0] = pack_bf2(C[0], C[1]);
                ap[1] = pack_bf2(C[2], C[3]);
            } else if (kg == 2) {
                *reinterpret_cast<unsigned*>(&acc_s[n][c * 10 + 8]) = pack_bf2(C[0], 0.f);
            }
        }

        // consume in-flight loads AFTER the MFMA block (vmcnt wait lands here),
        // write the OTHER xs buffer (its last readers finished before prev barrier)
        if (rd == 0)      { WRITE(1, vb, sb); ISSUE(2, va, sa); }
        else if (rd == 1) { WRITE(2, va, sa); ISSUE(3, vb, sb); }
        else if (rd == 2) { WRITE(3, vb, sb); }
        LDS_BARRIER();
    }
    #undef ISSUE
    #undef WRITE

    // ---- phase 2: C[256x16] = W[256xK'] * acc[K'x16], weight software-pipelined ----
    f32x4 C0 = {0.f, 0.f, 0.f, 0.f};
    f32x4 C1 = C0, C2 = C0, C3 = C0;

    // frag(i, ks) at wp + (i*NKS2 + ks)*512   (u16 units; 512 = 64 lanes * 8)
    const unsigned short* wp = g_whi + ((size_t)(wid * 4) * NKS2 * 64 + lane) * 8;

    bf16x8 wc[4];
    #pragma unroll
    for (int i = 0; i < 4; ++i)
        wc[i] = *(const bf16x8*)(wp + (size_t)i * NKS2 * 512);

    #pragma unroll
    for (int ks = 0; ks < NKS2; ++ks) {
        bf16x8 wn[4];
        if (ks + 1 < NKS2) {
            #pragma unroll
            for (int i = 0; i < 4; ++i)
                wn[i] = *(const bf16x8*)(wp + ((size_t)i * NKS2 + (ks + 1)) * 512);
        }
        const bf16x8 bhi = *(const bf16x8*)&acc_s[n][ks * 32 + kg * 8];
        C0 = __builtin_amdgcn_mfma_f32_16x16x32_bf16(wc[0], bhi, C0, 0, 0, 0);
        C1 = __builtin_amdgcn_mfma_f32_16x16x32_bf16(wc[1], bhi, C1, 0, 0, 0);
        C2 = __builtin_amdgcn_mfma_f32_16x16x32_bf16(wc[2], bhi, C2, 0, 0, 0);
        C3 = __builtin_amdgcn_mfma_f32_16x16x32_bf16(wc[3], bhi, C3, 0, 0, 0);
        if (ks + 1 < NKS2) {
            #pragma unroll
            for (int i = 0; i < 4; ++i) wc[i] = wn[i];
        }
    }

    // ---- epilogue: D layout col = lane&15, row = (lane>>4)*4 + reg ----
    #pragma unroll
    for (int i = 0; i < 4; ++i) {
        const f32x4 acc = (i == 0) ? C0 : (i == 1) ? C1 : (i == 2) ? C2 : C3;
        const int m0 = (wid * 4 + i) * 16 + kg * 4;
        #pragma unroll
        for (int r = 0; r < 4; ++r) {
            out[(size_t)(m0 + r) * (HOUT_ * WOUT_) + h * WOUT_ + w0 + n] = acc[r];
        }
    }
}

extern "C" void kernel_launch(void* const* d_in, const int* in_sizes, int n_in,
                              void* d_out, int out_size, void* d_ws, size_t ws_size,
                              hipStream_t stream)
{
    const float* x       = (const float*)d_in[0];
    const float* psi     = (const float*)d_in[1];
    const float* weight  = (const float*)d_in[2];
    const int*   hi_base = (const int*)d_in[3];
    float* out = (float*)d_out;

    hipLaunchKernelGGL(prep_weight_kernel, dim3(NMT * NKS2), dim3(64), 0, stream, weight);
    hipLaunchKernelGGL(prep_psi_kernel,    dim3(HOUT_),      dim3(64), 0, stream, psi);

    dim3 grid(45 * HOUT_, 1, 1);   // 16200, 1-D for XCD swizzle
    dim3 block(256, 1, 1);
    hipLaunchKernelGGL(disco_fused_kernel, grid, block, 0, stream,
                       x, hi_base, out);
}